// Round 1
// baseline (11.568 us; speedup 1.0000x reference)
//
#include <hip/hip_runtime.h>
#include <math.h>

// MMLU Llama head: RMSNorm(last token) -> 4-row GEMV -> softmax(4).
// Reference computes full-vocab GEMV but only option_ids rows survive;
// we compute exactly the 4 needed dot products. Total HBM traffic ~96 KB.

constexpr int D_MODEL = 4096;
constexpr int SEQ     = 2048;
constexpr int NOPT    = 4;

__global__ __launch_bounds__(1024) void mmlu_head_kernel(
    const float* __restrict__ x,        // [SEQ, D_MODEL]
    const float* __restrict__ nw,       // [D_MODEL]
    const float* __restrict__ hw,       // [VOCAB, D_MODEL]
    const int*   __restrict__ opt,      // [NOPT]
    float*       __restrict__ out)      // [NOPT]
{
    __shared__ float s_red[16];         // per-wave sumsq partials
    __shared__ float s_rms;
    __shared__ float s_dot[NOPT][4];    // per-option per-wave dot partials

    const int tid  = threadIdx.x;       // 0..1023
    const int lane = tid & 63;

    const float4* x4 = reinterpret_cast<const float4*>(x + (size_t)(SEQ - 1) * D_MODEL);
    const float4* w4 = reinterpret_cast<const float4*>(nw);

    // ---- Phase 1: sum of squares of last token row (4096 floats = 1024 float4) ----
    float4 v = x4[tid];
    float ss = v.x * v.x + v.y * v.y + v.z * v.z + v.w * v.w;
    #pragma unroll
    for (int o = 32; o > 0; o >>= 1) ss += __shfl_down(ss, o, 64);
    if (lane == 0) s_red[tid >> 6] = ss;
    __syncthreads();
    if (tid == 0) {
        float t = 0.f;
        #pragma unroll
        for (int i = 0; i < 16; ++i) t += s_red[i];
        s_rms = rsqrtf(t / (float)D_MODEL + 1e-5f);
    }

    // ---- Phase 2: 4 dot products, one 256-thread group per option ----
    const int g  = tid >> 8;            // option index 0..3
    const int gt = tid & 255;           // thread within group
    const int row = opt[g];
    const float4* h4 = reinterpret_cast<const float4*>(hw + (size_t)row * D_MODEL);

    float dot = 0.f;
    #pragma unroll
    for (int it = 0; it < 4; ++it) {
        int i = gt + it * 256;          // covers 1024 float4
        float4 a  = h4[i];
        float4 xv = x4[i];
        float4 wv = w4[i];
        dot += a.x * xv.x * wv.x + a.y * xv.y * wv.y
             + a.z * xv.z * wv.z + a.w * xv.w * wv.w;
    }
    #pragma unroll
    for (int o = 32; o > 0; o >>= 1) dot += __shfl_down(dot, o, 64);
    if (lane == 0) s_dot[g][(tid >> 6) & 3] = dot;
    __syncthreads();

    // ---- Phase 3: softmax over 4 logits ----
    if (tid == 0) {
        const float rms = s_rms;
        float logits[NOPT];
        float mx = -1e30f;
        #pragma unroll
        for (int k = 0; k < NOPT; ++k) {
            float d = (s_dot[k][0] + s_dot[k][1] + s_dot[k][2] + s_dot[k][3]) * rms;
            logits[k] = d;
            mx = fmaxf(mx, d);
        }
        float e[NOPT];
        float denom = 0.f;
        #pragma unroll
        for (int k = 0; k < NOPT; ++k) { e[k] = expf(logits[k] - mx); denom += e[k]; }
        #pragma unroll
        for (int k = 0; k < NOPT; ++k) out[k] = e[k] / denom;
    }
}

extern "C" void kernel_launch(void* const* d_in, const int* in_sizes, int n_in,
                              void* d_out, int out_size, void* d_ws, size_t ws_size,
                              hipStream_t stream) {
    const float* x   = (const float*)d_in[0];   // [2048, 4096] f32
    const float* nw  = (const float*)d_in[1];   // [4096] f32
    const float* hw  = (const float*)d_in[2];   // [128256, 4096] f32
    const int*   opt = (const int*)d_in[3];     // [4] i32
    float* out = (float*)d_out;                 // [4] f32

    mmlu_head_kernel<<<1, 1024, 0, stream>>>(x, nw, hw, opt, out);
}

// Round 2
// 9.274 us; speedup vs baseline: 1.2474x; 1.2474x over previous
//
#include <hip/hip_runtime.h>
#include <math.h>

// MMLU Llama head: RMSNorm(last token) -> 4-row GEMV -> softmax(4).
// Only the last token's row of x and the 4 option rows of head_weight are
// live; everything else in the reference is dead work. ~96 KB total traffic,
// single-block latency-bound kernel.
//
// R1 structure: ONE barrier. Phase 1 (sum of squares) and phase 2 (4 dot
// products of head_row . (x*w)) are independent because rms is applied as a
// scalar after reduction. opt[] is loaded first (wave-uniform -> s_load) so
// the head-row load chain starts immediately and overlaps the x/w loads.

constexpr int D_MODEL = 4096;
constexpr int SEQ     = 2048;
constexpr int NOPT    = 4;

__global__ __launch_bounds__(1024) void mmlu_head_kernel(
    const float* __restrict__ x,        // [SEQ, D_MODEL]
    const float* __restrict__ nw,       // [D_MODEL]
    const float* __restrict__ hw,       // [VOCAB, D_MODEL]
    const int*   __restrict__ opt,      // [NOPT]
    float*       __restrict__ out)      // [NOPT]
{
    __shared__ float s_red[16];         // per-wave sumsq partials
    __shared__ float s_dot[NOPT][4];    // per-option per-wave dot partials

    const int tid  = threadIdx.x;       // 0..1023
    const int lane = tid & 63;
    const int wid  = tid >> 6;          // 0..15
    const int g    = tid >> 8;          // option 0..3 (wave-uniform)
    const int gt   = tid & 255;         // thread within option group

    // Issue the option index load FIRST (wave-uniform -> scalar load), so the
    // dependent head-row loads start as early as possible.
    const int row = opt[g];
    const float4* h4 = reinterpret_cast<const float4*>(hw + (size_t)row * D_MODEL);

    const float4* x4 = reinterpret_cast<const float4*>(x + (size_t)(SEQ - 1) * D_MODEL);
    const float4* w4 = reinterpret_cast<const float4*>(nw);

    // ---- head-row dot partial: dot_g = sum_d hw[row][d] * x[d] * nw[d] ----
    float dot = 0.f;
    #pragma unroll
    for (int it = 0; it < 4; ++it) {
        int i = gt + it * 256;          // covers 1024 float4 per option
        float4 a  = h4[i];
        float4 xv = x4[i];
        float4 wv = w4[i];
        dot += a.x * xv.x * wv.x + a.y * xv.y * wv.y
             + a.z * xv.z * wv.z + a.w * xv.w * wv.w;
    }

    // ---- sum of squares of last-token row (independent of dot) ----
    float4 v = x4[tid];
    float ss = v.x * v.x + v.y * v.y + v.z * v.z + v.w * v.w;

    // ---- interleaved wave reductions ----
    #pragma unroll
    for (int o = 32; o > 0; o >>= 1) {
        ss  += __shfl_down(ss,  o, 64);
        dot += __shfl_down(dot, o, 64);
    }
    if (lane == 0) {
        s_red[wid] = ss;
        s_dot[g][wid & 3] = dot;
    }
    __syncthreads();

    // ---- final combine + softmax over 4 logits (thread 0) ----
    if (tid == 0) {
        float t = 0.f;
        #pragma unroll
        for (int i = 0; i < 16; ++i) t += s_red[i];
        const float rms = rsqrtf(t / (float)D_MODEL + 1e-5f);

        float logits[NOPT];
        float mx = -1e30f;
        #pragma unroll
        for (int k = 0; k < NOPT; ++k) {
            float d = (s_dot[k][0] + s_dot[k][1] + s_dot[k][2] + s_dot[k][3]) * rms;
            logits[k] = d;
            mx = fmaxf(mx, d);
        }
        float e[NOPT];
        float denom = 0.f;
        #pragma unroll
        for (int k = 0; k < NOPT; ++k) { e[k] = expf(logits[k] - mx); denom += e[k]; }
        #pragma unroll
        for (int k = 0; k < NOPT; ++k) out[k] = e[k] / denom;
    }
}

extern "C" void kernel_launch(void* const* d_in, const int* in_sizes, int n_in,
                              void* d_out, int out_size, void* d_ws, size_t ws_size,
                              hipStream_t stream) {
    const float* x   = (const float*)d_in[0];   // [2048, 4096] f32
    const float* nw  = (const float*)d_in[1];   // [4096] f32
    const float* hw  = (const float*)d_in[2];   // [128256, 4096] f32
    const int*   opt = (const int*)d_in[3];     // [4] i32
    float* out = (float*)d_out;                 // [4] f32

    mmlu_head_kernel<<<1, 1024, 0, stream>>>(x, nw, hw, opt, out);
}